// Round 8
// baseline (204.897 us; speedup 1.0000x reference)
//
#include <hip/hip_runtime.h>
#include <hip/hip_bf16.h>

// ---------------------------------------------------------------------------
// GATConv (PyG-style, H=2 heads, C=64, concat=False -> head mean) on gfx950.
// Phases:
//   0. k_wa     : WA[k][4] = W @ {att_s,att_d per head}  (logits = x @ WA)
//   1. k_gemm   : h = x@W via bf16 MFMA 16x16x32 (fused a_s/a_d via WA frag)
//   2. CSR build via two-level counting sort (no global atomics).
//   3. k_alpha  : per-dst wave: max-free esum + normalized fp32 alphas ->
//                 edata[head][off[d]+d + e] = {src<<8, alpha} (self slot at e=deg)
//   4. k_gat    : channel-chunked gather. 4 strips of 32ch (3.2MB < 4MB/XCD L2),
//                 blockIdx.y = strip (slow dim) -> strip stays L2-resident.
//                 Wave = 4 groups x 16 lanes = 4 edges in flight; atomicAdd
//                 0.5*head part onto bias-initialized out (k_init).
// ---------------------------------------------------------------------------

#define NBLK 256   // edge chunks (= threads in k_bscan)
#define TH 512     // threads for bhist/binsert
#define BSH 7      // bucket = dst >> 7
#define BSZ 128    // nodes per bucket
#define MAXBUCK 512
#define PLCAP 8192 // k_bucket LDS pair capacity (32 KB); avg bucket ~4224

typedef __attribute__((ext_vector_type(8))) short bf16x8;
typedef __attribute__((ext_vector_type(4))) float f32x4;

__device__ __forceinline__ ushort f2bf(float f) {
  __hip_bfloat16 b = __float2bfloat16(f);
  union { __hip_bfloat16 b; ushort u; } cv; cv.b = b; return cv.u;
}
__device__ __forceinline__ uint pk2(float a, float b) {
  return (uint)f2bf(a) | ((uint)f2bf(b) << 16);
}

// WA[k][0..3] = {W.att_s h0, W.att_s h1, W.att_d h0, W.att_d h1} as bf16
__global__ __launch_bounds__(128) void k_wa(const float* __restrict__ W,
                                            const float* __restrict__ as,
                                            const float* __restrict__ ad,
                                            ushort* __restrict__ wa) {
  const int k = threadIdx.x;  // 0..127
  float s0 = 0.f, s1 = 0.f, d0 = 0.f, d1 = 0.f;
  const float* wr = &W[k * 128];
  for (int c = 0; c < 64; ++c) {
    float w0 = wr[c], w1 = wr[64 + c];
    s0 = fmaf(w0, as[c], s0);
    s1 = fmaf(w1, as[64 + c], s1);
    d0 = fmaf(w0, ad[c], d0);
    d1 = fmaf(w1, ad[64 + c], d1);
  }
  wa[k * 4 + 0] = f2bf(s0);
  wa[k * 4 + 1] = f2bf(s1);
  wa[k * 4 + 2] = f2bf(d0);
  wa[k * 4 + 3] = f2bf(d1);
}

// h = x @ W via bf16 MFMA; fused a_s/a_d via WA fragment (wave 3).
__global__ __launch_bounds__(256) void k_gemm(
    const float* __restrict__ x, const float* __restrict__ W,
    const ushort* __restrict__ wa, __hip_bfloat162* __restrict__ h2,
    float* __restrict__ a_s, float* __restrict__ a_d, int Nn) {
  __shared__ ushort Al[64 * 128];  // 16 KB, XOR-swizzled bf16 x-tile
  char* lb = (char*)Al;
  const int wave = threadIdx.x >> 6;
  const int lane = threadIdx.x & 63;
  const int row0 = blockIdx.x * 64;
  const int l15 = lane & 15;
  const int kb = (lane >> 4) * 8;  // k-offset of this lane's frag elements

  // ---- stage x tile: fp32 -> bf16 LDS, swizzled ----
  {
    const int t = threadIdx.x;
    const int srow = t >> 2, q = t & 3;
    int gr = row0 + srow; gr = (gr < Nn) ? gr : (Nn - 1);
    const float4* xr = (const float4*)&x[(size_t)gr * 128 + q * 32];
#pragma unroll
    for (int i = 0; i < 4; ++i) {
      float4 v0 = xr[2 * i], v1 = xr[2 * i + 1];
      uint4 w;
      w.x = pk2(v0.x, v0.y); w.y = pk2(v0.z, v0.w);
      w.z = pk2(v1.x, v1.y); w.w = pk2(v1.z, v1.w);
      int byte = srow * 256 + ((q * 64 + i * 16) ^ ((srow & 7) << 4));
      *(uint4*)(lb + byte) = w;
    }
  }

  // ---- B fragments (W) in registers: 2 col-tiles x 4 k-steps ----
  bf16x8 bfr[2][4];
#pragma unroll
  for (int c = 0; c < 2; ++c) {
#pragma unroll
    for (int ks = 0; ks < 4; ++ks) {
      const float* wp = &W[(ks * 32 + kb) * 128 + wave * 32 + c * 16 + l15];
      union { bf16x8 v; ushort u[8]; } t;
#pragma unroll
      for (int j = 0; j < 8; ++j) t.u[j] = f2bf(wp[j * 128]);
      bfr[c][ks] = t.v;
    }
  }
  // WA fragment (wave 3 only)
  bf16x8 wafr[4];
  if (wave == 3) {
#pragma unroll
    for (int ks = 0; ks < 4; ++ks) {
      union { bf16x8 v; ushort u[8]; } t;
#pragma unroll
      for (int j = 0; j < 8; ++j)
        t.u[j] = (l15 < 4) ? wa[(ks * 32 + kb + j) * 4 + l15] : (ushort)0;
      wafr[ks] = t.v;
    }
  }

  __syncthreads();

  // ---- MFMA main loop ----
  f32x4 acc[4][2];
  f32x4 accwa[4];
#pragma unroll
  for (int r = 0; r < 4; ++r) {
    acc[r][0] = (f32x4){0.f, 0.f, 0.f, 0.f};
    acc[r][1] = (f32x4){0.f, 0.f, 0.f, 0.f};
    accwa[r] = (f32x4){0.f, 0.f, 0.f, 0.f};
  }
#pragma unroll
  for (int ks = 0; ks < 4; ++ks) {
    bf16x8 af[4];
#pragma unroll
    for (int r = 0; r < 4; ++r) {
      int row = r * 16 + l15;
      int byte = row * 256 + ((ks * 64 + (lane >> 4) * 16) ^ ((row & 7) << 4));
      uint4 v = *(const uint4*)(lb + byte);
      union { uint4 q; bf16x8 v; } cv; cv.q = v;
      af[r] = cv.v;
    }
#pragma unroll
    for (int r = 0; r < 4; ++r) {
      acc[r][0] = __builtin_amdgcn_mfma_f32_16x16x32_bf16(af[r], bfr[0][ks],
                                                          acc[r][0], 0, 0, 0);
      acc[r][1] = __builtin_amdgcn_mfma_f32_16x16x32_bf16(af[r], bfr[1][ks],
                                                          acc[r][1], 0, 0, 0);
    }
    if (wave == 3) {
#pragma unroll
      for (int r = 0; r < 4; ++r)
        accwa[r] = __builtin_amdgcn_mfma_f32_16x16x32_bf16(af[r], wafr[ks],
                                                           accwa[r], 0, 0, 0);
    }
  }

  // ---- store h (bf16, direct) ----
  ushort* hs = (ushort*)h2;
  const int rbase = (lane >> 4) * 4;
#pragma unroll
  for (int r = 0; r < 4; ++r) {
#pragma unroll
    for (int c = 0; c < 2; ++c) {
      int col = wave * 32 + c * 16 + l15;
#pragma unroll
      for (int i = 0; i < 4; ++i) {
        int grow = row0 + r * 16 + rbase + i;
        if (grow < Nn) hs[(size_t)grow * 128 + col] = f2bf(acc[r][c][i]);
      }
    }
  }
  // ---- store a_s / a_d from WA accumulators ----
  if (wave == 3) {
#pragma unroll
    for (int r = 0; r < 4; ++r) {
#pragma unroll
      for (int i = 0; i < 4; ++i) {
        int grow = row0 + r * 16 + rbase + i;
        if (grow < Nn) {
          float v = accwa[r][i];
          if (l15 < 2) a_s[grow * 2 + l15] = v;
          else if (l15 < 4) a_d[grow * 2 + (l15 - 2)] = v;
        }
      }
    }
  }
}

// per-chunk LDS histogram over buckets -> bhist[bucket][chunk]
__global__ __launch_bounds__(TH) void k_bhist(const int* __restrict__ dst,
                                              int* __restrict__ bhist, int E,
                                              int nbuck, int chunk) {
  __shared__ int hl[MAXBUCK];
  for (int i = threadIdx.x; i < nbuck; i += TH) hl[i] = 0;
  __syncthreads();
  const int s = blockIdx.x * chunk;
  const int e = (s + chunk < E) ? s + chunk : E;
  for (int i = s + threadIdx.x; i < e; i += TH)
    atomicAdd(&hl[dst[i] >> BSH], 1);
  __syncthreads();
  for (int b = threadIdx.x; b < nbuck; b += TH)
    bhist[b * NBLK + blockIdx.x] = hl[b];
}

// per bucket: exclusive scan over chunks -> raw cursors; write bucket total
__global__ __launch_bounds__(NBLK) void k_bscan(const int* __restrict__ bhist,
                                                int* __restrict__ cursors,
                                                int* __restrict__ totals,
                                                int nbuck) {
  __shared__ int tmp[NBLK];
  const int b = blockIdx.x;
  const int t = threadIdx.x;
  const int v = bhist[b * NBLK + t];
  tmp[t] = v;
  __syncthreads();
  for (int d = 1; d < NBLK; d <<= 1) {
    int add = (t >= d) ? tmp[t - d] : 0;
    __syncthreads();
    tmp[t] += add;
    __syncthreads();
  }
  cursors[t * nbuck + b] = tmp[t] - v;  // raw (no base)
  if (t == NBLK - 1) totals[b] = tmp[t];
}

// exclusive scan of bucket totals -> bases[0..nbuck]
__global__ __launch_bounds__(MAXBUCK) void k_bbase(const int* __restrict__ totals,
                                                   int* __restrict__ bases,
                                                   int nbuck) {
  __shared__ int tmp[MAXBUCK];
  const int t = threadIdx.x;
  const int v = (t < nbuck) ? totals[t] : 0;
  tmp[t] = v;
  __syncthreads();
  for (int d = 1; d < MAXBUCK; d <<= 1) {
    int add = (t >= d) ? tmp[t - d] : 0;
    __syncthreads();
    tmp[t] += add;
    __syncthreads();
  }
  if (t < nbuck) bases[t] = tmp[t] - v;
  if (t == nbuck - 1) bases[nbuck] = tmp[t];
}

// scatter packed (local_dst<<16 | src) into bucket-grouped pairs array
__global__ __launch_bounds__(TH) void k_binsert(
    const int* __restrict__ src, const int* __restrict__ dst,
    const int* __restrict__ cursors, const int* __restrict__ bases,
    int* __restrict__ pairs, int E, int nbuck, int chunk) {
  __shared__ int cur[MAXBUCK];
  for (int i = threadIdx.x; i < nbuck; i += TH)
    cur[i] = cursors[blockIdx.x * nbuck + i] + bases[i];
  __syncthreads();
  const int s = blockIdx.x * chunk;
  const int e = (s + chunk < E) ? s + chunk : E;
  for (int i = s + threadIdx.x; i < e; i += TH) {
    const int d = dst[i];
    const int b = d >> BSH;
    const int p = atomicAdd(&cur[b], 1);
    pairs[p] = ((d & (BSZ - 1)) << 16) | src[i];
  }
}

// per bucket: single-pass (pairs staged in LDS): count+scan -> off/cnt, then
// LDS-sourced scatter into csr. Fallback to two global passes if oversized.
__global__ __launch_bounds__(256) void k_bucket(
    const int* __restrict__ pairs, const int* __restrict__ bases,
    int* __restrict__ off, int* __restrict__ cnt, int* __restrict__ csr,
    int Nn) {
  __shared__ int pl[PLCAP];  // 32 KB
  __shared__ int cl[BSZ];
  __shared__ int tmp[BSZ];
  __shared__ int cu[BSZ];
  const int b = blockIdx.x;
  const int t = threadIdx.x;
  const int n0 = b << BSH;
  if (t < BSZ) cl[t] = 0;
  __syncthreads();
  const int s = bases[b], e = bases[b + 1];
  const int len = e - s;
  const bool fit = (len <= PLCAP);
  if (fit) {
    for (int i = t; i < len; i += 256) {
      int pv = pairs[s + i];
      pl[i] = pv;
      atomicAdd(&cl[pv >> 16], 1);
    }
  } else {
    for (int i = s + t; i < e; i += 256) atomicAdd(&cl[pairs[i] >> 16], 1);
  }
  __syncthreads();
  int v = 0;
  if (t < BSZ) { v = cl[t]; tmp[t] = v; }
  __syncthreads();
  for (int d = 1; d < BSZ; d <<= 1) {
    int add = (t < BSZ && t >= d) ? tmp[t - d] : 0;
    __syncthreads();
    if (t < BSZ) tmp[t] += add;
    __syncthreads();
  }
  if (t < BSZ) {
    const int excl = tmp[t] - v;
    cu[t] = s + excl;
    const int node = n0 + t;
    if (node < Nn) { off[node] = s + excl; cnt[node] = v; }
  }
  __syncthreads();
  if (fit) {
    for (int i = t; i < len; i += 256) {
      const int pv = pl[i];
      const int p = atomicAdd(&cu[pv >> 16], 1);
      csr[p] = pv & 0xffff;
    }
  } else {
    for (int i = s + t; i < e; i += 256) {
      const int pv = pairs[i];
      const int p = atomicAdd(&cu[pv >> 16], 1);
      csr[p] = pv & 0xffff;
    }
  }
}

__device__ __forceinline__ float leaky02(float v) {
  return fmaxf(v, 0.2f * v);  // slope 0.2 leaky relu (valid for both signs)
}

// out[i] = bias[i % 64]
__global__ __launch_bounds__(256) void k_init(float* __restrict__ out,
                                              const float* __restrict__ bias,
                                              int total) {
  int i = blockIdx.x * 256 + threadIdx.x;
  if (i < total) out[i] = bias[i & 63];
}

// One wave per dst: max-free esum, then write normalized alphas per head:
// edata[h][off[d]+d + e] = {src<<8, alpha}; self slot at e=deg.
__global__ __launch_bounds__(256) void k_alpha(
    const float* __restrict__ a_s, const float* __restrict__ a_d,
    const int* __restrict__ off, const int* __restrict__ cnt,
    const int* __restrict__ csr, uint2* __restrict__ ed0,
    uint2* __restrict__ ed1, int Nn) {
  const int wave = threadIdx.x >> 6;
  const int lane = threadIdx.x & 63;
  const int d = blockIdx.x * 4 + wave;
  if (d >= Nn) return;
  const int o = off[d], deg = cnt[d];
  const int o2 = o + d;
  const float2 ad2 = *(const float2*)&a_d[d * 2];
  float sw0 = 0.f, sw1 = 0.f;
  for (int e = lane; e < deg; e += 64) {
    int sl = csr[o + e];
    float2 as2 = *(const float2*)&a_s[sl * 2];
    sw0 += __expf(leaky02(as2.x + ad2.x));
    sw1 += __expf(leaky02(as2.y + ad2.y));
  }
#pragma unroll
  for (int m = 1; m <= 32; m <<= 1) {
    sw0 += __shfl_xor(sw0, m, 64);
    sw1 += __shfl_xor(sw1, m, 64);
  }
  const float2 asd = *(const float2*)&a_s[d * 2];
  const float ws0 = __expf(leaky02(asd.x + ad2.x));
  const float ws1 = __expf(leaky02(asd.y + ad2.y));
  const float inv0 = 1.f / (sw0 + ws0 + 1e-16f);
  const float inv1 = 1.f / (sw1 + ws1 + 1e-16f);
  for (int e = lane; e < deg; e += 64) {
    int sl = csr[o + e];
    float2 as2 = *(const float2*)&a_s[sl * 2];
    float w0 = __expf(leaky02(as2.x + ad2.x));
    float w1 = __expf(leaky02(as2.y + ad2.y));
    ed0[o2 + e] = make_uint2((uint)sl << 8, __float_as_uint(w0 * inv0));
    ed1[o2 + e] = make_uint2((uint)sl << 8, __float_as_uint(w1 * inv1));
  }
  if (lane == 0) {
    ed0[o2 + deg] = make_uint2((uint)d << 8, __float_as_uint(ws0 * inv0));
    ed1[o2 + deg] = make_uint2((uint)d << 8, __float_as_uint(ws1 * inv1));
  }
}

// Channel-chunked gather: blockIdx.y = chunk (head = c>>1, half = c&1).
// Wave = 4 groups x 16 lanes; each group handles one edge's 32-ch strip.
__global__ __launch_bounds__(256) void k_gat(
    const __hip_bfloat162* __restrict__ h2, const uint2* __restrict__ ed0,
    const uint2* __restrict__ ed1, const int* __restrict__ off,
    const int* __restrict__ cnt, float* __restrict__ out, int Nn) {
  const int wave = threadIdx.x >> 6;
  const int lane = threadIdx.x & 63;
  const int d = blockIdx.x * 4 + wave;
  if (d >= Nn) return;
  const int c = blockIdx.y;  // 0..3
  const uint2* __restrict__ ed = (c >> 1) ? ed1 : ed0;
  const int n = cnt[d] + 1;          // incl. self slot
  const int o2 = off[d] + d;
  const char* hb = (const char*)h2;
  const uint claneoff =
      (uint)((c >> 1) * 128 + (c & 1) * 64 + (lane & 15) * 4);
  const int g = lane >> 4;
  float acc0 = 0.f, acc1 = 0.f;
  int e = 0;
  for (; e + 16 <= n; e += 16) {  // unguarded fast path, 4 gathers in flight
    uint2 e0 = ed[o2 + e + g];
    uint2 e1 = ed[o2 + e + 4 + g];
    uint2 e2 = ed[o2 + e + 8 + g];
    uint2 e3 = ed[o2 + e + 12 + g];
    uint v0 = *(const uint*)(hb + (size_t)(e0.x + claneoff));
    uint v1 = *(const uint*)(hb + (size_t)(e1.x + claneoff));
    uint v2 = *(const uint*)(hb + (size_t)(e2.x + claneoff));
    uint v3 = *(const uint*)(hb + (size_t)(e3.x + claneoff));
    float a0 = __uint_as_float(e0.y), a1 = __uint_as_float(e1.y);
    float a2 = __uint_as_float(e2.y), a3 = __uint_as_float(e3.y);
    acc0 = fmaf(a0, __uint_as_float(v0 << 16), acc0);
    acc1 = fmaf(a0, __uint_as_float(v0 & 0xffff0000u), acc1);
    acc0 = fmaf(a1, __uint_as_float(v1 << 16), acc0);
    acc1 = fmaf(a1, __uint_as_float(v1 & 0xffff0000u), acc1);
    acc0 = fmaf(a2, __uint_as_float(v2 << 16), acc0);
    acc1 = fmaf(a2, __uint_as_float(v2 & 0xffff0000u), acc1);
    acc0 = fmaf(a3, __uint_as_float(v3 << 16), acc0);
    acc1 = fmaf(a3, __uint_as_float(v3 & 0xffff0000u), acc1);
  }
  for (; e < n; e += 4) {  // guarded tail
    int idx = e + g;
    uint2 e0 = ed[o2 + ((idx < n) ? idx : n - 1)];
    float a0 = (idx < n) ? __uint_as_float(e0.y) : 0.f;
    uint v0 = *(const uint*)(hb + (size_t)(e0.x + claneoff));
    acc0 = fmaf(a0, __uint_as_float(v0 << 16), acc0);
    acc1 = fmaf(a0, __uint_as_float(v0 & 0xffff0000u), acc1);
  }
  // reduce the 4 groups (lanes l, l+16, l+32, l+48 share a channel pair)
  acc0 += __shfl_xor(acc0, 16, 64);
  acc0 += __shfl_xor(acc0, 32, 64);
  acc1 += __shfl_xor(acc1, 16, 64);
  acc1 += __shfl_xor(acc1, 32, 64);
  if (lane < 16) {
    float* op = &out[(size_t)d * 64 + (c & 1) * 32 + lane * 2];
    atomicAdd(op, 0.5f * acc0);
    atomicAdd(op + 1, 0.5f * acc1);
  }
}

extern "C" void kernel_launch(void* const* d_in, const int* in_sizes, int n_in,
                              void* d_out, int out_size, void* d_ws,
                              size_t ws_size, hipStream_t stream) {
  const float* x = (const float*)d_in[0];
  const float* W = (const float*)d_in[1];
  const float* att_s = (const float*)d_in[2];
  const float* att_d = (const float*)d_in[3];
  const float* bias = (const float*)d_in[4];
  const int* ei = (const int*)d_in[5];
  const int Nn = in_sizes[0] / 128;
  const int E = in_sizes[5] / 2;
  const int* src = ei;
  const int* dst = ei + E;
  float* out = (float*)d_out;

  const int nbuck = (Nn + BSZ - 1) >> BSH;          // 391 for N=50000
  const int chunk = (E + NBLK - 1) / NBLK;          // 6250 for E=1.6M

  // workspace layout (~54 MB)
  __hip_bfloat162* h2 = (__hip_bfloat162*)d_ws;     // N*64 bf16x2 (12.8MB)
  float* a_s = (float*)(h2 + (size_t)Nn * 64);      // N*2
  float* a_d = a_s + (size_t)Nn * 2;                // N*2
  int* off = (int*)(a_d + (size_t)Nn * 2);          // N
  int* cnt = off + Nn;                              // N
  int* bhist = cnt + Nn;                            // nbuck*NBLK
  int* cursors = bhist + (size_t)nbuck * NBLK;      // NBLK*nbuck
  int* totals = cursors + (size_t)NBLK * nbuck;     // nbuck
  int* bases = totals + nbuck;                      // nbuck+1
  ushort* wa = (ushort*)(bases + nbuck + 1);        // 512 bf16
  int* pairs = (int*)(wa + 512);                    // E
  int* csr = pairs + (size_t)E;                     // E
  uint2* ed0 = (uint2*)(csr + (size_t)E);           // E+N (13.2MB)
  uint2* ed1 = ed0 + (size_t)(E + Nn);              // E+N (13.2MB)

  const int ndb = (Nn + 3) / 4;  // dst-wave blocks

  hipLaunchKernelGGL(k_wa, dim3(1), dim3(128), 0, stream, W, att_s, att_d, wa);
  hipLaunchKernelGGL(k_gemm, dim3((Nn + 63) / 64), dim3(256), 0, stream, x, W,
                     wa, h2, a_s, a_d, Nn);
  hipLaunchKernelGGL(k_bhist, dim3(NBLK), dim3(TH), 0, stream, dst, bhist, E,
                     nbuck, chunk);
  hipLaunchKernelGGL(k_bscan, dim3(nbuck), dim3(NBLK), 0, stream, bhist,
                     cursors, totals, nbuck);
  hipLaunchKernelGGL(k_bbase, dim3(1), dim3(MAXBUCK), 0, stream, totals, bases,
                     nbuck);
  hipLaunchKernelGGL(k_binsert, dim3(NBLK), dim3(TH), 0, stream, src, dst,
                     cursors, bases, pairs, E, nbuck, chunk);
  hipLaunchKernelGGL(k_bucket, dim3(nbuck), dim3(256), 0, stream, pairs, bases,
                     off, cnt, csr, Nn);
  hipLaunchKernelGGL(k_init, dim3((Nn * 64 + 255) / 256), dim3(256), 0, stream,
                     out, bias, Nn * 64);
  hipLaunchKernelGGL(k_alpha, dim3(ndb), dim3(256), 0, stream, a_s, a_d, off,
                     cnt, csr, ed0, ed1, Nn);
  hipLaunchKernelGGL(k_gat, dim3(ndb, 4), dim3(256), 0, stream, h2, ed0, ed1,
                     off, cnt, out, Nn);
}

// Round 9
// 141.338 us; speedup vs baseline: 1.4497x; 1.4497x over previous
//
#include <hip/hip_runtime.h>
#include <hip/hip_bf16.h>

// ---------------------------------------------------------------------------
// GATConv (PyG-style, H=2 heads, C=64, concat=False -> head mean) on gfx950.
// Phases:
//   0. k_wa     : WA[k][4] = W @ {att_s,att_d per head}  (logits = x @ WA)
//   1. k_gemm   : h = x@W via bf16 MFMA 16x16x32 (fused a_s/a_d via WA frag)
//   2. CSR build via two-level counting sort (no global atomics):
//        k_bhist/k_bscan/k_bbase/k_binsert as before; k_bucket now ALSO
//        computes per-node esum (LDS ds_add_f32) and writes PRE-NORMALIZED
//        alphas: edAB[off[d]+d+rank] = {src<<8, a0, src<<8, a1} (16B/edge,
//        self slot at rank=deg). a_s/a_d gathers are L2-resident (400KB).
//   3. k_aggr   : pure gather. Per 64 edges: 1 coalesced 16B edAB load +
//                 2 ds_writes; head-split LDS broadcast (ewA/ewB, 2-way =
//                 free); inner loop reads 1 uint4 = 2 edges, full 256B h row
//                 per wave instruction; 16 gathers in flight. No exp, no
//                 normalization (alphas pre-normalized), no esum reduce.
// ---------------------------------------------------------------------------

#define NBLK 256   // edge chunks (= threads in k_bscan)
#define TH 512     // threads for bhist/binsert
#define BSH 7      // bucket = dst >> 7
#define BSZ 128    // nodes per bucket
#define MAXBUCK 512
#define PLCAP 8192 // k_bucket LDS pair capacity (32 KB); avg bucket ~4224

typedef __attribute__((ext_vector_type(8))) short bf16x8;
typedef __attribute__((ext_vector_type(4))) float f32x4;

__device__ __forceinline__ ushort f2bf(float f) {
  __hip_bfloat16 b = __float2bfloat16(f);
  union { __hip_bfloat16 b; ushort u; } cv; cv.b = b; return cv.u;
}
__device__ __forceinline__ uint pk2(float a, float b) {
  return (uint)f2bf(a) | ((uint)f2bf(b) << 16);
}

// WA[k][0..3] = {W.att_s h0, W.att_s h1, W.att_d h0, W.att_d h1} as bf16
__global__ __launch_bounds__(128) void k_wa(const float* __restrict__ W,
                                            const float* __restrict__ as,
                                            const float* __restrict__ ad,
                                            ushort* __restrict__ wa) {
  const int k = threadIdx.x;  // 0..127
  float s0 = 0.f, s1 = 0.f, d0 = 0.f, d1 = 0.f;
  const float* wr = &W[k * 128];
  for (int c = 0; c < 64; ++c) {
    float w0 = wr[c], w1 = wr[64 + c];
    s0 = fmaf(w0, as[c], s0);
    s1 = fmaf(w1, as[64 + c], s1);
    d0 = fmaf(w0, ad[c], d0);
    d1 = fmaf(w1, ad[64 + c], d1);
  }
  wa[k * 4 + 0] = f2bf(s0);
  wa[k * 4 + 1] = f2bf(s1);
  wa[k * 4 + 2] = f2bf(d0);
  wa[k * 4 + 3] = f2bf(d1);
}

// h = x @ W via bf16 MFMA; fused a_s/a_d via WA fragment (wave 3).
__global__ __launch_bounds__(256) void k_gemm(
    const float* __restrict__ x, const float* __restrict__ W,
    const ushort* __restrict__ wa, __hip_bfloat162* __restrict__ h2,
    float* __restrict__ a_s, float* __restrict__ a_d, int Nn) {
  __shared__ ushort Al[64 * 128];  // 16 KB, XOR-swizzled bf16 x-tile
  char* lb = (char*)Al;
  const int wave = threadIdx.x >> 6;
  const int lane = threadIdx.x & 63;
  const int row0 = blockIdx.x * 64;
  const int l15 = lane & 15;
  const int kb = (lane >> 4) * 8;  // k-offset of this lane's frag elements

  // ---- stage x tile: fp32 -> bf16 LDS, swizzled ----
  {
    const int t = threadIdx.x;
    const int srow = t >> 2, q = t & 3;
    int gr = row0 + srow; gr = (gr < Nn) ? gr : (Nn - 1);
    const float4* xr = (const float4*)&x[(size_t)gr * 128 + q * 32];
#pragma unroll
    for (int i = 0; i < 4; ++i) {
      float4 v0 = xr[2 * i], v1 = xr[2 * i + 1];
      uint4 w;
      w.x = pk2(v0.x, v0.y); w.y = pk2(v0.z, v0.w);
      w.z = pk2(v1.x, v1.y); w.w = pk2(v1.z, v1.w);
      int byte = srow * 256 + ((q * 64 + i * 16) ^ ((srow & 7) << 4));
      *(uint4*)(lb + byte) = w;
    }
  }

  // ---- B fragments (W) in registers: 2 col-tiles x 4 k-steps ----
  bf16x8 bfr[2][4];
#pragma unroll
  for (int c = 0; c < 2; ++c) {
#pragma unroll
    for (int ks = 0; ks < 4; ++ks) {
      const float* wp = &W[(ks * 32 + kb) * 128 + wave * 32 + c * 16 + l15];
      union { bf16x8 v; ushort u[8]; } t;
#pragma unroll
      for (int j = 0; j < 8; ++j) t.u[j] = f2bf(wp[j * 128]);
      bfr[c][ks] = t.v;
    }
  }
  // WA fragment (wave 3 only)
  bf16x8 wafr[4];
  if (wave == 3) {
#pragma unroll
    for (int ks = 0; ks < 4; ++ks) {
      union { bf16x8 v; ushort u[8]; } t;
#pragma unroll
      for (int j = 0; j < 8; ++j)
        t.u[j] = (l15 < 4) ? wa[(ks * 32 + kb + j) * 4 + l15] : (ushort)0;
      wafr[ks] = t.v;
    }
  }

  __syncthreads();

  // ---- MFMA main loop ----
  f32x4 acc[4][2];
  f32x4 accwa[4];
#pragma unroll
  for (int r = 0; r < 4; ++r) {
    acc[r][0] = (f32x4){0.f, 0.f, 0.f, 0.f};
    acc[r][1] = (f32x4){0.f, 0.f, 0.f, 0.f};
    accwa[r] = (f32x4){0.f, 0.f, 0.f, 0.f};
  }
#pragma unroll
  for (int ks = 0; ks < 4; ++ks) {
    bf16x8 af[4];
#pragma unroll
    for (int r = 0; r < 4; ++r) {
      int row = r * 16 + l15;
      int byte = row * 256 + ((ks * 64 + (lane >> 4) * 16) ^ ((row & 7) << 4));
      uint4 v = *(const uint4*)(lb + byte);
      union { uint4 q; bf16x8 v; } cv; cv.q = v;
      af[r] = cv.v;
    }
#pragma unroll
    for (int r = 0; r < 4; ++r) {
      acc[r][0] = __builtin_amdgcn_mfma_f32_16x16x32_bf16(af[r], bfr[0][ks],
                                                          acc[r][0], 0, 0, 0);
      acc[r][1] = __builtin_amdgcn_mfma_f32_16x16x32_bf16(af[r], bfr[1][ks],
                                                          acc[r][1], 0, 0, 0);
    }
    if (wave == 3) {
#pragma unroll
      for (int r = 0; r < 4; ++r)
        accwa[r] = __builtin_amdgcn_mfma_f32_16x16x32_bf16(af[r], wafr[ks],
                                                           accwa[r], 0, 0, 0);
    }
  }

  // ---- store h (bf16, direct) ----
  ushort* hs = (ushort*)h2;
  const int rbase = (lane >> 4) * 4;
#pragma unroll
  for (int r = 0; r < 4; ++r) {
#pragma unroll
    for (int c = 0; c < 2; ++c) {
      int col = wave * 32 + c * 16 + l15;
#pragma unroll
      for (int i = 0; i < 4; ++i) {
        int grow = row0 + r * 16 + rbase + i;
        if (grow < Nn) hs[(size_t)grow * 128 + col] = f2bf(acc[r][c][i]);
      }
    }
  }
  // ---- store a_s / a_d from WA accumulators ----
  if (wave == 3) {
#pragma unroll
    for (int r = 0; r < 4; ++r) {
#pragma unroll
      for (int i = 0; i < 4; ++i) {
        int grow = row0 + r * 16 + rbase + i;
        if (grow < Nn) {
          float v = accwa[r][i];
          if (l15 < 2) a_s[grow * 2 + l15] = v;
          else if (l15 < 4) a_d[grow * 2 + (l15 - 2)] = v;
        }
      }
    }
  }
}

// per-chunk LDS histogram over buckets -> bhist[bucket][chunk]
__global__ __launch_bounds__(TH) void k_bhist(const int* __restrict__ dst,
                                              int* __restrict__ bhist, int E,
                                              int nbuck, int chunk) {
  __shared__ int hl[MAXBUCK];
  for (int i = threadIdx.x; i < nbuck; i += TH) hl[i] = 0;
  __syncthreads();
  const int s = blockIdx.x * chunk;
  const int e = (s + chunk < E) ? s + chunk : E;
  for (int i = s + threadIdx.x; i < e; i += TH)
    atomicAdd(&hl[dst[i] >> BSH], 1);
  __syncthreads();
  for (int b = threadIdx.x; b < nbuck; b += TH)
    bhist[b * NBLK + blockIdx.x] = hl[b];
}

// per bucket: exclusive scan over chunks -> raw cursors; write bucket total
__global__ __launch_bounds__(NBLK) void k_bscan(const int* __restrict__ bhist,
                                                int* __restrict__ cursors,
                                                int* __restrict__ totals,
                                                int nbuck) {
  __shared__ int tmp[NBLK];
  const int b = blockIdx.x;
  const int t = threadIdx.x;
  const int v = bhist[b * NBLK + t];
  tmp[t] = v;
  __syncthreads();
  for (int d = 1; d < NBLK; d <<= 1) {
    int add = (t >= d) ? tmp[t - d] : 0;
    __syncthreads();
    tmp[t] += add;
    __syncthreads();
  }
  cursors[t * nbuck + b] = tmp[t] - v;  // raw (no base)
  if (t == NBLK - 1) totals[b] = tmp[t];
}

// exclusive scan of bucket totals -> bases[0..nbuck]
__global__ __launch_bounds__(MAXBUCK) void k_bbase(const int* __restrict__ totals,
                                                   int* __restrict__ bases,
                                                   int nbuck) {
  __shared__ int tmp[MAXBUCK];
  const int t = threadIdx.x;
  const int v = (t < nbuck) ? totals[t] : 0;
  tmp[t] = v;
  __syncthreads();
  for (int d = 1; d < MAXBUCK; d <<= 1) {
    int add = (t >= d) ? tmp[t - d] : 0;
    __syncthreads();
    tmp[t] += add;
    __syncthreads();
  }
  if (t < nbuck) bases[t] = tmp[t] - v;
  if (t == nbuck - 1) bases[nbuck] = tmp[t];
}

// scatter packed (local_dst<<16 | src) into bucket-grouped pairs array
__global__ __launch_bounds__(TH) void k_binsert(
    const int* __restrict__ src, const int* __restrict__ dst,
    const int* __restrict__ cursors, const int* __restrict__ bases,
    int* __restrict__ pairs, int E, int nbuck, int chunk) {
  __shared__ int cur[MAXBUCK];
  for (int i = threadIdx.x; i < nbuck; i += TH)
    cur[i] = cursors[blockIdx.x * nbuck + i] + bases[i];
  __syncthreads();
  const int s = blockIdx.x * chunk;
  const int e = (s + chunk < E) ? s + chunk : E;
  for (int i = s + threadIdx.x; i < e; i += TH) {
    const int d = dst[i];
    const int b = d >> BSH;
    const int p = atomicAdd(&cur[b], 1);
    pairs[p] = ((d & (BSZ - 1)) << 16) | src[i];
  }
}

__device__ __forceinline__ float leaky02(float v) {
  return fmaxf(v, 0.2f * v);  // slope 0.2 leaky relu (valid for both signs)
}

// per bucket: count + per-node esum (LDS float atomics) -> off/cnt + inv,
// then scatter PRE-NORMALIZED alphas: edAB[csr_pos + node] =
// {src<<8, a0, src<<8, a1}. Self slot at rank=deg. a_s/a_d gathers hit L2.
__global__ __launch_bounds__(256) void k_bucket(
    const int* __restrict__ pairs, const int* __restrict__ bases,
    const float* __restrict__ a_s, const float* __restrict__ a_d,
    int* __restrict__ off, int* __restrict__ cnt, uint4* __restrict__ edAB,
    int Nn) {
  __shared__ int pl[PLCAP];  // 32 KB
  __shared__ int cl[BSZ];
  __shared__ int tmp[BSZ];
  __shared__ int cu[BSZ];
  __shared__ float es0[BSZ], es1[BSZ];
  __shared__ float inv0l[BSZ], inv1l[BSZ];
  __shared__ float adl0[BSZ], adl1[BSZ];
  const int b = blockIdx.x;
  const int t = threadIdx.x;
  const int n0 = b << BSH;
  if (t < BSZ) {
    cl[t] = 0; es0[t] = 0.f; es1[t] = 0.f;
    const int node = n0 + t;
    float2 ad2 = make_float2(0.f, 0.f);
    if (node < Nn) ad2 = *(const float2*)&a_d[node * 2];
    adl0[t] = ad2.x; adl1[t] = ad2.y;
  }
  __syncthreads();
  const int s = bases[b], e = bases[b + 1];
  const int len = e - s;
  const bool fit = (len <= PLCAP);
  // pass 1: count + esum accumulate
  for (int i = t; i < len; i += 256) {
    const int pv = pairs[s + i];
    if (fit) pl[i] = pv;
    const int ld = pv >> 16, sr = pv & 0xffff;
    atomicAdd(&cl[ld], 1);
    float2 as2 = *(const float2*)&a_s[sr * 2];
    atomicAdd(&es0[ld], __expf(leaky02(as2.x + adl0[ld])));
    atomicAdd(&es1[ld], __expf(leaky02(as2.y + adl1[ld])));
  }
  __syncthreads();
  int v = 0;
  if (t < BSZ) { v = cl[t]; tmp[t] = v; }
  __syncthreads();
  for (int d = 1; d < BSZ; d <<= 1) {
    int add = (t < BSZ && t >= d) ? tmp[t - d] : 0;
    __syncthreads();
    if (t < BSZ) tmp[t] += add;
    __syncthreads();
  }
  if (t < BSZ) {
    const int excl = tmp[t] - v;
    cu[t] = s + excl;  // csr position cursor
    const int node = n0 + t;
    if (node < Nn) {
      off[node] = s + excl;
      cnt[node] = v;
      float2 asd = *(const float2*)&a_s[node * 2];
      const float ws0 = __expf(leaky02(asd.x + adl0[t]));
      const float ws1 = __expf(leaky02(asd.y + adl1[t]));
      const float i0 = 1.f / (es0[t] + ws0 + 1e-16f);
      const float i1 = 1.f / (es1[t] + ws1 + 1e-16f);
      inv0l[t] = i0; inv1l[t] = i1;
      // self slot: edata idx = csr_pos_end + node = (s+excl+v) + node
      const size_t sidx = (size_t)(s + excl + v) + node;
      edAB[sidx] = make_uint4((uint)node << 8, __float_as_uint(ws0 * i0),
                              (uint)node << 8, __float_as_uint(ws1 * i1));
    }
  }
  __syncthreads();
  // pass 2: scatter pre-normalized alphas (recompute exp; a_s now L2-hot)
  for (int i = t; i < len; i += 256) {
    const int pv = fit ? pl[i] : pairs[s + i];
    const int ld = pv >> 16, sr = pv & 0xffff;
    float2 as2 = *(const float2*)&a_s[sr * 2];
    const float w0 = __expf(leaky02(as2.x + adl0[ld]));
    const float w1 = __expf(leaky02(as2.y + adl1[ld]));
    const int p = atomicAdd(&cu[ld], 1);
    const size_t gi = (size_t)p + (n0 + ld);  // edata idx = csr_pos + node
    edAB[gi] = make_uint4((uint)sr << 8, __float_as_uint(w0 * inv0l[ld]),
                          (uint)sr << 8, __float_as_uint(w1 * inv1l[ld]));
  }
}

// One wave per dst. Pure gather: staging = 1 coalesced 16B edAB load +
// 2 ds_writes per 64 edges; inner loop = R7 head-split broadcast, 16 gathers
// in flight. Alphas pre-normalized -> no exp / no esum reduce / no inv.
__global__ __launch_bounds__(256) void k_aggr(
    const __hip_bfloat162* __restrict__ h2, const uint4* __restrict__ edAB,
    const int* __restrict__ off, const int* __restrict__ cnt,
    const float* __restrict__ bias, float* __restrict__ out, int Nn) {
  __shared__ uint2 ewA[4][64];  // 2 KB
  __shared__ uint2 ewB[4][64];  // 2 KB
  const int wave = threadIdx.x >> 6;
  const int lane = threadIdx.x & 63;
  const int d = blockIdx.x * 4 + wave;
  if (d >= Nn) return;
  const int o2 = off[d] + d;       // edata base (self slots before d)
  const int n = cnt[d] + 1;        // incl. self slot
  const char* hb = (const char*)h2;
  const unsigned l4 = lane * 4u;
  const uint4* ebase = (lane < 32) ? (const uint4*)&ewA[wave][0]
                                   : (const uint4*)&ewB[wave][0];
  float acc0 = 0.f, acc1 = 0.f;

  for (int c = 0; c < n; c += 64) {
    int rem = n - c; if (rem > 64) rem = 64;
    {
      uint4 tld = make_uint4(0, 0, 0, 0);
      if (lane < rem) tld = edAB[(size_t)o2 + c + lane];  // 16B coalesced
      ewA[wave][lane] = make_uint2(tld.x, tld.y);
      ewB[wave][lane] = make_uint2(tld.z, tld.w);
    }
    // each uint4 from LDS = TWO edges {voffA,aA,voffB,aB}; lanes<32 cover
    // channels 0..63 (head0, weights from ewA), lanes>=32 channels 64..127
    // (head1, ewB); same voff both halves -> one 256B row per wave-instr.
    const int nq = (rem + 1) >> 1;
    int q = 0;
    for (; q + 8 <= nq; q += 8) {  // 16 gathers in flight
      uint4 p[8];
#pragma unroll
      for (int u = 0; u < 8; ++u) p[u] = ebase[q + u];
      uint va[8], vb[8];
#pragma unroll
      for (int u = 0; u < 8; ++u) {
        va[u] = *(const uint*)(hb + (size_t)(p[u].x + l4));
        vb[u] = *(const uint*)(hb + (size_t)(p[u].z + l4));
      }
#pragma unroll
      for (int u = 0; u < 8; ++u) {
        const float aa = __uint_as_float(p[u].y);
        const float ab = __uint_as_float(p[u].w);
        acc0 = fmaf(aa, __uint_as_float(va[u] << 16), acc0);
        acc1 = fmaf(aa, __uint_as_float(va[u] & 0xffff0000u), acc1);
        acc0 = fmaf(ab, __uint_as_float(vb[u] << 16), acc0);
        acc1 = fmaf(ab, __uint_as_float(vb[u] & 0xffff0000u), acc1);
      }
    }
    for (; q < nq; ++q) {
      uint4 p = ebase[q];
      uint va = *(const uint*)(hb + (size_t)(p.x + l4));
      uint vb = *(const uint*)(hb + (size_t)(p.z + l4));
      acc0 = fmaf(__uint_as_float(p.y), __uint_as_float(va << 16), acc0);
      acc1 = fmaf(__uint_as_float(p.y), __uint_as_float(va & 0xffff0000u), acc1);
      acc0 = fmaf(__uint_as_float(p.w), __uint_as_float(vb << 16), acc0);
      acc1 = fmaf(__uint_as_float(p.w), __uint_as_float(vb & 0xffff0000u), acc1);
    }
  }
  // head mean: lane l (<32, head0 ch 2l,2l+1) + lane l+32 (head1 ch 2l,2l+1)
  float o0 = acc0 + __shfl_down(acc0, 32, 64);
  float o1 = acc1 + __shfl_down(acc1, 32, 64);
  if (lane < 32) {
    int c = lane * 2;
    float2 res = make_float2(0.5f * o0 + bias[c], 0.5f * o1 + bias[c + 1]);
    *(float2*)&out[(size_t)d * 64 + c] = res;
  }
}

extern "C" void kernel_launch(void* const* d_in, const int* in_sizes, int n_in,
                              void* d_out, int out_size, void* d_ws,
                              size_t ws_size, hipStream_t stream) {
  const float* x = (const float*)d_in[0];
  const float* W = (const float*)d_in[1];
  const float* att_s = (const float*)d_in[2];
  const float* att_d = (const float*)d_in[3];
  const float* bias = (const float*)d_in[4];
  const int* ei = (const int*)d_in[5];
  const int Nn = in_sizes[0] / 128;
  const int E = in_sizes[5] / 2;
  const int* src = ei;
  const int* dst = ei + E;
  float* out = (float*)d_out;

  const int nbuck = (Nn + BSZ - 1) >> BSH;          // 391 for N=50000
  const int chunk = (E + NBLK - 1) / NBLK;          // 6250 for E=1.6M

  // workspace layout (~47 MB)
  __hip_bfloat162* h2 = (__hip_bfloat162*)d_ws;     // N*64 bf16x2 (12.8MB)
  uint4* edAB = (uint4*)(h2 + (size_t)Nn * 64);     // (E+N)*16B (26.4MB)
  float* a_s = (float*)(edAB + (size_t)(E + Nn));   // N*2
  float* a_d = a_s + (size_t)Nn * 2;                // N*2
  int* off = (int*)(a_d + (size_t)Nn * 2);          // N
  int* cnt = off + Nn;                              // N
  int* bhist = cnt + Nn;                            // nbuck*NBLK
  int* cursors = bhist + (size_t)nbuck * NBLK;      // NBLK*nbuck
  int* totals = cursors + (size_t)NBLK * nbuck;     // nbuck
  int* bases = totals + nbuck;                      // nbuck+1
  ushort* wa = (ushort*)(bases + nbuck + 1);        // 512 bf16
  int* pairs = (int*)(wa + 512);                    // E

  const int ndb = (Nn + 3) / 4;  // dst-wave blocks

  hipLaunchKernelGGL(k_wa, dim3(1), dim3(128), 0, stream, W, att_s, att_d, wa);
  hipLaunchKernelGGL(k_gemm, dim3((Nn + 63) / 64), dim3(256), 0, stream, x, W,
                     wa, h2, a_s, a_d, Nn);
  hipLaunchKernelGGL(k_bhist, dim3(NBLK), dim3(TH), 0, stream, dst, bhist, E,
                     nbuck, chunk);
  hipLaunchKernelGGL(k_bscan, dim3(nbuck), dim3(NBLK), 0, stream, bhist,
                     cursors, totals, nbuck);
  hipLaunchKernelGGL(k_bbase, dim3(1), dim3(MAXBUCK), 0, stream, totals, bases,
                     nbuck);
  hipLaunchKernelGGL(k_binsert, dim3(NBLK), dim3(TH), 0, stream, src, dst,
                     cursors, bases, pairs, E, nbuck, chunk);
  hipLaunchKernelGGL(k_bucket, dim3(nbuck), dim3(256), 0, stream, pairs, bases,
                     a_s, a_d, off, cnt, edAB, Nn);
  hipLaunchKernelGGL(k_aggr, dim3(ndb), dim3(256), 0, stream, h2, edAB, off,
                     cnt, bias, out, Nn);
}